// Round 2
// baseline (140.158 us; speedup 1.0000x reference)
//
#include <hip/hip_runtime.h>
#include <stdint.h>

#define N 8192
#define C 512
#define BM 256                        /* rows per block (4 waves x 64 rows) */
#define BN 128
#define BKF 128                       /* fp8 bytes per K-tile */
#define NSPLIT 8
#define COLS_PER_SPLIT (N / NSPLIT)   /* 1024 */
#define CT (COLS_PER_SPLIT / BN)      /* 8 */
#define GRID_GEMM ((N / BM) * NSPLIT) /* 256 = 1 block/CU, single round */
#define INV_T 14.285714285714286f

typedef __attribute__((ext_vector_type(4)))  int   i32x4;
typedef __attribute__((ext_vector_type(8)))  int   i32x8;
typedef __attribute__((ext_vector_type(16))) float f32x16;

// ---- fused prep: fp32 -> fp8 e4m3 (HW cvt) for X and Y + exact fp32 pos ----
// Also zeroes out + the rb merge counters (replaces the memset dispatch).
__global__ __launch_bounds__(256) void prep_kernel(const float* __restrict__ X,
                                                   const float* __restrict__ Y,
                                                   unsigned char* __restrict__ Xf8,
                                                   unsigned char* __restrict__ Yf8,
                                                   float* __restrict__ pos,
                                                   int* __restrict__ cnt,
                                                   float* __restrict__ out) {
  if (blockIdx.x == 0) {
    if (threadIdx.x < (N / BM)) cnt[threadIdx.x] = 0;
    if (threadIdx.x == 64) *out = 0.0f;
  }
  const int wave = threadIdx.x >> 6;
  const int lane = threadIdx.x & 63;
  const int row = blockIdx.x * 4 + wave;
  const float4* xr = (const float4*)(X + (size_t)row * C) + lane * 2;
  const float4* yr = (const float4*)(Y + (size_t)row * C) + lane * 2;
  float4 x0 = xr[0], x1 = xr[1];
  float4 y0 = yr[0], y1 = yr[1];
  float s = x0.x * y0.x + x0.y * y0.y + x0.z * y0.z + x0.w * y0.w
          + x1.x * y1.x + x1.y * y1.y + x1.z * y1.z + x1.w * y1.w;
  int2 ox, oy;
  ox.x = __builtin_amdgcn_cvt_pk_fp8_f32(x0.x, x0.y, 0, false);
  ox.x = __builtin_amdgcn_cvt_pk_fp8_f32(x0.z, x0.w, ox.x, true);
  ox.y = __builtin_amdgcn_cvt_pk_fp8_f32(x1.x, x1.y, 0, false);
  ox.y = __builtin_amdgcn_cvt_pk_fp8_f32(x1.z, x1.w, ox.y, true);
  oy.x = __builtin_amdgcn_cvt_pk_fp8_f32(y0.x, y0.y, 0, false);
  oy.x = __builtin_amdgcn_cvt_pk_fp8_f32(y0.z, y0.w, oy.x, true);
  oy.y = __builtin_amdgcn_cvt_pk_fp8_f32(y1.x, y1.y, 0, false);
  oy.y = __builtin_amdgcn_cvt_pk_fp8_f32(y1.z, y1.w, oy.y, true);
  ((int2*)(Xf8 + (size_t)row * C))[lane] = ox;
  ((int2*)(Yf8 + (size_t)row * C))[lane] = oy;
#pragma unroll
  for (int off = 32; off >= 1; off >>= 1) s += __shfl_xor(s, off);
  if (lane == 0) pos[row] = s * INV_T;
}

// ---- main: MX-scaled fp8 MFMA + online lse + fused last-block combine ----
// v3 structure: wave owns 64 rows x 128 cols (2 A row-sets in regs, shared B
// fragment feeds 2 MFMAs -> LDS bytes/MFMA halved to 1KB). 1 block/CU,
// ~350 VGPR, 1 wave/SIMD — ILP-driven. B dbuf + counted vmcnt(4) + raw
// barriers unchanged from verified v2. Last block per rb merges partials.
__global__ __launch_bounds__(256, 1) void gemm_lse_kernel(const unsigned char* __restrict__ Xf8,
                                                          const unsigned char* __restrict__ Yf8,
                                                          float2* __restrict__ partials,
                                                          const float* __restrict__ pos,
                                                          int* __restrict__ cnt,
                                                          float* __restrict__ out) {
  __shared__ unsigned char Bs[2][BN][BKF];   // 32 KB double-buffered B k-tile
  __shared__ float wsum[4];
  __shared__ int mflag;

  const int tid = threadIdx.x;
  const int bx = blockIdx.x;
  const int split = bx & (NSPLIT - 1);      // XCD = bx%8 = split -> L2 locality
  const int rb = bx >> 3;                   // 0..31
  const int row0 = rb * BM;
  const int colbase = split * COLS_PER_SPLIT;

  const int w = tid >> 6;                   // wave 0..3: rows [w*64, +64)
  const int lane = tid & 63;
  const int lrow = lane & 31;
  const int h = lane >> 5;                  // k-half selector
  const int swz = lrow & 7;

  // ---- A for this wave: 2 row-sets x full K=512, into registers ----
  // lane holds bytes [kk*64 + h*32, +32) of rows (row0+w*64+lrow) and +32.
  i32x4 tL0[8], tH0[8], tL1[8], tH1[8];
  {
    const unsigned char* a0 = Xf8 + (size_t)(row0 + w * 64 + lrow) * C + h * 32;
    const unsigned char* a1 = a0 + (size_t)32 * C;
#pragma unroll
    for (int kk = 0; kk < 8; ++kk) {
      asm volatile("global_load_dwordx4 %0, %1, off"
                   : "=v"(tL0[kk]) : "v"(a0 + kk * 64));
      asm volatile("global_load_dwordx4 %0, %1, off offset:16"
                   : "=v"(tH0[kk]) : "v"(a0 + kk * 64));
      asm volatile("global_load_dwordx4 %0, %1, off"
                   : "=v"(tL1[kk]) : "v"(a1 + kk * 64));
      asm volatile("global_load_dwordx4 %0, %1, off offset:16"
                   : "=v"(tH1[kk]) : "v"(a1 + kk * 64));
    }
  }

  // B staging-lane invariants (pre-swizzled global source, linear LDS dest)
  const int r_base = tid >> 3;              // row within 32-row group
  const int p = tid & 7;
  const int j = p ^ (r_base & 7);

  auto stageB = [&](int buf, int col0, int k0) {
#pragma unroll
    for (int i = 0; i < 4; ++i) {
      const int r = i * 32 + r_base;
      const unsigned char* gb = Yf8 + (size_t)(col0 + r) * C + k0 * BKF + j * 16;
      uint32_t loff = (uint32_t)((i * 256 + (tid & ~63)) * 16);
      __builtin_amdgcn_global_load_lds(
          (const __attribute__((address_space(1))) uint32_t*)(uintptr_t)gb,
          (__attribute__((address_space(3))) uint32_t*)(uintptr_t)((char*)&Bs[buf][0][0] + loff),
          16, 0, 0);
    }
  };

  // prologue: stage tile (ct=0,k0=0) into buf0; drain EVERYTHING (incl. the
  // asm A-loads the compiler can't track) exactly once.
  stageB(0, colbase, 0);
  asm volatile("s_waitcnt vmcnt(0)" ::: "memory");
  __builtin_amdgcn_sched_barrier(0);
  __builtin_amdgcn_s_barrier();
  __builtin_amdgcn_sched_barrier(0);

  // pack A fragments once (temps die here; zero per-iteration packing movs)
  i32x8 aF0[8], aF1[8];
#pragma unroll
  for (int kk = 0; kk < 8; ++kk) {
    aF0[kk] = (i32x8){ tL0[kk][0], tL0[kk][1], tL0[kk][2], tL0[kk][3],
                       tH0[kk][0], tH0[kk][1], tH0[kk][2], tH0[kk][3] };
    aF1[kk] = (i32x8){ tL1[kk][0], tL1[kk][1], tL1[kk][2], tL1[kk][3],
                       tH1[kk][0], tH1[kk][1], tH1[kk][2], tH1[kk][3] };
  }

  float m0[16], l0[16], m1[16], l1[16];
#pragma unroll
  for (int s = 0; s < 16; ++s) {
    m0[s] = -INFINITY; l0[s] = 0.0f;
    m1[s] = -INFINITY; l1[s] = 0.0f;
  }

  for (int ct = 0; ct < CT; ++ct) {
    f32x16 acc0[4], acc1[4];
#pragma unroll
    for (int t = 0; t < 4; ++t)
#pragma unroll
      for (int e = 0; e < 16; ++e) { acc0[t][e] = 0.0f; acc1[t][e] = 0.0f; }

#pragma unroll
    for (int k0 = 0; k0 < 4; ++k0) {      // tile (ct,k0) lives in Bs[k0&1]
      const int nct = (k0 == 3) ? ((ct + 1) & (CT - 1)) : ct;
      const int nk0 = (k0 + 1) & 3;
      stageB((k0 + 1) & 1, colbase + nct * BN, nk0);
      __builtin_amdgcn_sched_barrier(0);
      asm volatile("s_waitcnt vmcnt(4)" ::: "memory");
      __builtin_amdgcn_s_barrier();
      __builtin_amdgcn_sched_barrier(0);

      __builtin_amdgcn_s_setprio(1);
#pragma unroll
      for (int s = 0; s < 2; ++s) {       // two K=64 steps per 128B segment
        const int kk = 2 * k0 + s;
        const int c0 = 4 * s + 2 * h;
#pragma unroll
        for (int tj = 0; tj < 4; ++tj) {
          const int brow = tj * 32 + lrow;
          i32x4 blo = *(const i32x4*)&Bs[k0 & 1][brow][((c0    ) ^ swz) * 16];
          i32x4 bhi = *(const i32x4*)&Bs[k0 & 1][brow][((c0 + 1) ^ swz) * 16];
          i32x8 bf = { blo[0], blo[1], blo[2], blo[3], bhi[0], bhi[1], bhi[2], bhi[3] };
          acc0[tj] = __builtin_amdgcn_mfma_scale_f32_32x32x64_f8f6f4(
              aF0[kk], bf, acc0[tj], 0, 0, 0, 127, 0, 127);
          acc1[tj] = __builtin_amdgcn_mfma_scale_f32_32x32x64_f8f6f4(
              aF1[kk], bf, acc1[tj], 0, 0, 0, 127, 0, 127);
        }
      }
      __builtin_amdgcn_s_setprio(0);
      __builtin_amdgcn_sched_barrier(0);
      __builtin_amdgcn_s_barrier();       // reads done before next overwrite
      __builtin_amdgcn_sched_barrier(0);
    }

    // per-lane online update over this 128-col tile (both row-sets)
#pragma unroll
    for (int r = 0; r < 16; ++r) {
      {
        float v0 = acc0[0][r] * INV_T, v1 = acc0[1][r] * INV_T;
        float v2 = acc0[2][r] * INV_T, v3 = acc0[3][r] * INV_T;
        float mx = fmaxf(fmaxf(v0, v1), fmaxf(v2, v3));
        float mn = fmaxf(m0[r], mx);
        l0[r] = l0[r] * __expf(m0[r] - mn)
              + __expf(v0 - mn) + __expf(v1 - mn) + __expf(v2 - mn) + __expf(v3 - mn);
        m0[r] = mn;
      }
      {
        float v0 = acc1[0][r] * INV_T, v1 = acc1[1][r] * INV_T;
        float v2 = acc1[2][r] * INV_T, v3 = acc1[3][r] * INV_T;
        float mx = fmaxf(fmaxf(v0, v1), fmaxf(v2, v3));
        float mn = fmaxf(m1[r], mx);
        l1[r] = l1[r] * __expf(m1[r] - mn)
              + __expf(v0 - mn) + __expf(v1 - mn) + __expf(v2 - mn) + __expf(v3 - mn);
        m1[r] = mn;
      }
    }
  }

  // drain the dangling wrap-prefetch
  asm volatile("s_waitcnt vmcnt(0)" ::: "memory");

  // merge across the 32 lanes (cols) sharing each row-set
#pragma unroll
  for (int r = 0; r < 16; ++r) {
    float ma = m0[r], la = l0[r], mb = m1[r], lb = l1[r];
#pragma unroll
    for (int off = 1; off < 32; off <<= 1) {
      float mo = __shfl_xor(ma, off), lo = __shfl_xor(la, off);
      float mn = fmaxf(ma, mo);
      la = la * __expf(ma - mn) + lo * __expf(mo - mn);
      ma = mn;
      float mo2 = __shfl_xor(mb, off), lo2 = __shfl_xor(lb, off);
      float mn2 = fmaxf(mb, mo2);
      lb = lb * __expf(mb - mn2) + lo2 * __expf(mo2 - mn2);
      mb = mn2;
    }
    m0[r] = ma; l0[r] = la; m1[r] = mb; l1[r] = lb;
  }
  if (lrow == 0) {
#pragma unroll
    for (int r = 0; r < 16; ++r) {
      int row_local = (r & 3) + 8 * (r >> 2) + 4 * h;
      int base = row0 + w * 64;
      partials[(size_t)split * N + (base + row_local)]      = make_float2(m0[r], l0[r]);
      partials[(size_t)split * N + (base + 32 + row_local)] = make_float2(m1[r], l1[r]);
    }
  }

  // ---- fused combine: last block for this rb merges all NSPLIT partials ----
  __syncthreads();
  if (tid == 0) {
    __threadfence();
    int old = atomicAdd(&cnt[rb], 1);
    mflag = (old == NSPLIT - 1) ? 1 : 0;
  }
  __syncthreads();
  if (mflag) {
    __threadfence();
    int row = row0 + tid;                 // 256 threads, 256 rows
    float M = -INFINITY, L = 0.0f;
#pragma unroll
    for (int s = 0; s < NSPLIT; ++s) {
      float2 pr = partials[(size_t)s * N + row];
      float mn = fmaxf(M, pr.x);
      L = L * __expf(M - mn) + pr.y * __expf(pr.x - mn);
      M = mn;
    }
    float v = M + __logf(L) - pos[row];
#pragma unroll
    for (int off = 32; off >= 1; off >>= 1) v += __shfl_xor(v, off);
    if (lane == 0) wsum[w] = v;
    __syncthreads();
    if (tid == 0) atomicAdd(out, wsum[0] + wsum[1] + wsum[2] + wsum[3]);
  }
}

extern "C" void kernel_launch(void* const* d_in, const int* in_sizes, int n_in,
                              void* d_out, int out_size, void* d_ws, size_t ws_size,
                              hipStream_t stream) {
  const float* X = (const float*)d_in[0];
  const float* Y = (const float*)d_in[1];
  float* out = (float*)d_out;

  // workspace: Xf8 (4MB) | Yf8 (4MB) | partials (512KB) | pos (32KB) | cnt
  char* w = (char*)d_ws;
  unsigned char* Xf8 = (unsigned char*)w;
  unsigned char* Yf8 = Xf8 + (size_t)N * C;
  float2* partials = (float2*)(Yf8 + (size_t)N * C);
  float* pos = (float*)((char*)partials + (size_t)NSPLIT * N * sizeof(float2));
  int* cnt = (int*)(pos + N);

  prep_kernel<<<N / 4, 256, 0, stream>>>(X, Y, Xf8, Yf8, pos, cnt, out);
  gemm_lse_kernel<<<GRID_GEMM, 256, 0, stream>>>(Xf8, Yf8, partials, pos, cnt, out);
}